// Round 2
// baseline (510.184 us; speedup 1.0000x reference)
//
#include <hip/hip_runtime.h>

#define N_ 2000
#define L_ 1024

__device__ __forceinline__ float rcpf(float d) { return __builtin_amdgcn_rcpf(d); }
__device__ __forceinline__ float ex2(float x)  { return __builtin_amdgcn_exp2f(x); }

// One FULL chain per lane. All four gates (m,n,h,y) are independent given Vn,
// so merging both halves of the old lane-pair into one lane adds ILP (fills
// dependent-latency stalls of a lone wave) without lengthening the serial
// V -> rates -> gates -> V critical path. No cross-lane ops remain.
// STEP1: K = timestep (consumes z[K-1], stores out row K), RS = (K-1)&7.
#define STEP1(K, RS)                                                          \
  {                                                                           \
    const int kk = (K);                                                       \
    float zc = zb[RS];                                                        \
    int kpre = kk + 7;                                                        \
    int kc = kpre < 1998 ? kpre : 1998;                                       \
    zb[RS] = z[base + kc * L_];                                               \
    /* conductances: G = DT/2*(GNA m^3 h + GK n^4 + GL + GS y), E likewise */ \
    float m2   = m * m;                                                       \
    float m3   = m2 * m;                                                      \
    float valm = m3 * h;          /* m^3 h */                                 \
    float n2   = n * n;                                                       \
    float valn = n2 * n2;         /* n^4 */                                   \
    float gy   = __fmaf_rn(y, 0.01f, 0.003f);                                 \
    float G    = __fmaf_rn(valm, 0.4f, __fmaf_rn(valn, 0.35f, gy));           \
    float E    = __fmaf_rn(valm, 2200.0f, __fmaf_rn(valn, -2695.0f, -19.5f)); \
    float num  = __fmaf_rn(V, 1.0f - G, __fmaf_rn(E, 0.02f, 0.02f));          \
    float Vn   = num * rcpf(1.0f + G);                                        \
    /* M rates: eRm = exp((Vn+35)/9); aM=0.182*ur*eRm, s1m=0.01*(aM+bM) */    \
    float eRm  = ex2(__fmaf_rn(Vn, K9, 35.0f * K9));                          \
    float um   = Vn + 35.0f;                                                  \
    float urm  = um * rcpf(eRm - 1.0f);                                       \
    bool  patm = (Vn == -35.0f);                                              \
    float aM   = patm ? 1.638f   : 0.182f * (urm * eRm);                      \
    float s1m  = patm ? 0.02798f : urm * __fmaf_rn(0.00182f, eRm, 0.00124f);  \
    /* N rates: eRn = exp((Vn-25)/9) */                                       \
    float eRn  = ex2(__fmaf_rn(Vn, K9, -25.0f * K9));                         \
    float un   = Vn - 25.0f;                                                  \
    float urn  = un * rcpf(eRn - 1.0f);                                       \
    bool  patn = (Vn == 25.0f);                                               \
    float aN   = patn ? 0.18f   : 0.02f * (urn * eRn);                        \
    float s1n  = patn ? 0.0026f : urn * __fmaf_rn(0.0002f, eRn, 0.00002f);    \
    /* H rates */                                                             \
    float aH   = 0.25f * ex2(__fmaf_rn(Vn, -K12, -90.0f * K12));              \
    float bH   = 0.25f * ex2(__fmaf_rn(Vn,  K12,  34.0f * K12));              \
    /* trapezoidal gate updates */                                            \
    float qm   = 1.0f + s1m;                                                  \
    float numm = __fmaf_rn(aM, 0.02f, __fmaf_rn(-s1m, m, m));                 \
    float qn   = 1.0f + s1n;                                                  \
    float numn = __fmaf_rn(aN, 0.02f, __fmaf_rn(-s1n, n, n));                 \
    float sh   = __fmaf_rn(aH, 0.01f, 0.01f * bH);                            \
    float qh   = 1.0f + sh;                                                   \
    float numh = __fmaf_rn(aH, 0.02f, __fmaf_rn(-sh, h, h));                  \
    float sy   = __fmaf_rn(zc, 0.01f, 0.001f);                                \
    float qy   = 1.0f + sy;                                                   \
    float numy = __fmaf_rn(zc, 0.02f, __fmaf_rn(-sy, y, y));                  \
    float rq1  = rcpf(qm * qh);                                               \
    m = numm * (rq1 * qh);                                                    \
    h = numh * (rq1 * qm);                                                    \
    float rq2  = rcpf(qn * qy);                                               \
    n = numn * (rq2 * qy);                                                    \
    y = numy * (rq2 * qn);                                                    \
    V = Vn;                                                                   \
    /* sigmoid((Vn+20)/3) = t/(1+t), t = eRm^3 * e^-5 */                      \
    float e2 = eRm * eRm;                                                     \
    float ts = (e2 * eRm) * 0.006737946999085467f;                            \
    float sg = ts * rcpf(1.0f + ts);                                          \
    out[base + kk * L_] = sg;                                                 \
  }

__global__ __launch_bounds__(64) void hh_kernel(const float* __restrict__ z,
                                                float* __restrict__ out) {
    const int t   = blockIdx.x * 64 + threadIdx.x;   // chain 0..16383
    const int b   = t >> 10;
    const int l   = t & 1023;
    const int base = b * (N_ * L_) + l;

    const float K9  = 0.16029944898766259f;   // log2(e)/9
    const float K12 = 0.12022458674074695f;   // log2(e)/12

    float V = -70.0f;
    float m = 0.0f, n = 0.0f, h = 1.0f, y = 0.0f;

    float zb[8];
#pragma unroll
    for (int i = 0; i < 8; ++i) zb[i] = z[base + i * L_];

    // row 0: sigmoid((-70+20)/3), constant
    out[base] = 5.777750e-8f;

    int k = 1;
    for (int g = 0; g < 249; ++g) {          // K = 1 .. 1992
#pragma unroll
        for (int j = 0; j < 8; ++j) {
            STEP1(k + j, j)
        }
        k += 8;
    }
    // k == 1993: K = 1993 .. 1999 (ring slots 0..6)
#pragma unroll
    for (int j = 0; j < 7; ++j) {
        STEP1(k + j, j)
    }
}

extern "C" void kernel_launch(void* const* d_in, const int* in_sizes, int n_in,
                              void* d_out, int out_size, void* d_ws, size_t ws_size,
                              hipStream_t stream) {
    const float* z = (const float*)d_in[0];
    float* out = (float*)d_out;
    // 16384 chains x 1 lane = 16384 threads = 256 waves (1 per CU)
    hh_kernel<<<256, 64, 0, stream>>>(z, out);
}

// Round 3
// 504.735 us; speedup vs baseline: 1.0108x; 1.0108x over previous
//
#include <hip/hip_runtime.h>

#define N_ 2000
#define L_ 1024

__device__ __forceinline__ float rcpf(float d) { return __builtin_amdgcn_rcpf(d); }
__device__ __forceinline__ float ex2(float x)  { return __builtin_amdgcn_exp2f(x); }

// quad_perm DPP cross-lane moves (VALU latency, no DS pipe).
__device__ __forceinline__ float dpp_bcast2(float x) {  // all lanes <- quad lane 2
    return __int_as_float(__builtin_amdgcn_mov_dpp(__float_as_int(x), 0xAA, 0xF, 0xF, true));
}
__device__ __forceinline__ float dpp_x1(float x) {      // lane ^ 1
    return __int_as_float(__builtin_amdgcn_mov_dpp(__float_as_int(x), 0xB1, 0xF, 0xF, true));
}
__device__ __forceinline__ float dpp_x2(float x) {      // lane ^ 2
    return __int_as_float(__builtin_amdgcn_mov_dpp(__float_as_int(x), 0x4E, 0xF, 0xF, true));
}

// One chain per 4-lane QUAD: lane0=m, lane1=n, lane2=h, lane3=y + output store.
// G,E built by quad DPP reduction; Vn duplicated on all 4 lanes.
// Straight-line code; per-lane behavior steered by loop-invariant constants.
#define STEP1(RS, DOLOAD)                                                     \
  {                                                                           \
    float zc = zb[RS];                                                        \
    if (DOLOAD) { zb[RS] = *zpre; zpre += L_; }                               \
    /* G/E partials from pre-update state */                                  \
    float hX  = dpp_bcast2(st);            /* h to all lanes of quad */       \
    float s2v = st * st;                                                      \
    float v3h = (s2v * st) * hX;           /* m^3 h   (lane0) */              \
    float v4  = s2v * s2v;                 /* n^4     (lane1) */              \
    float val = isM ? v3h : (isN ? v4 : st);                                  \
    float gP  = __fmaf_rn(val, cg, cgad);                                     \
    float eP  = __fmaf_rn(val, ce, cead);                                     \
    gP += dpp_x1(gP); gP += dpp_x2(gP);    /* quad sum -> all lanes */        \
    eP += dpp_x1(eP); eP += dpp_x2(eP);                                       \
    float num = __fmaf_rn(V, 1.0f - gP, __fmaf_rn(eP, 0.02f, 0.02f));         \
    float Vn  = num * rcpf(1.0f + gP);                                        \
    /* per-lane rate exps: eA = eRm | eRn | aH/.25 | sigmoid-t */             \
    float eA  = ex2(__fmaf_rn(Vn, sA1, cA1));                                 \
    float eB  = ex2(__fmaf_rn(Vn, sB1, cB1));   /* bH/.25 on lane2 */         \
    float rr  = rcpf(eA + cD);             /* 1/(eR-1) | 1/(1+t) */           \
    float u   = Vn + cu;                                                      \
    /* s = DT/2*(a+b): u*(ks0+ks1*rr) | 0.0025(eA+eB) | 0.01 zc+0.001 */      \
    float X    = __fmaf_rn(ks1, rr, ks0);                                     \
    float sAux = __fmaf_rn(kse, eA + eB, cS);                                 \
    sAux       = __fmaf_rn(zm01, zc, sAux);                                   \
    float s    = __fmaf_rn(u, X, sAux);                                       \
    /* a-rate: kA*u*(1+rr) | 0.25*eA | zc */                                  \
    float p   = kA * u;                                                       \
    float aRw = __fmaf_rn(p, rr, p);                                          \
    float a2  = __fmaf_rn(k2, eA, aRw);                                       \
    a2        = __fmaf_rn(zm, zc, a2);                                        \
    bool pat  = (Vn == cc);                /* exact singularity patch */      \
    s  = pat ? pS : s;                                                        \
    a2 = pat ? pA : a2;                                                       \
    /* trapezoidal gate update */                                             \
    float q    = 1.0f + s;                                                    \
    float numr = __fmaf_rn(a2, 0.02f, __fmaf_rn(-s, st, st));                 \
    st = numr * rcpf(q);                                                      \
    V  = Vn;                                                                  \
    /* lane3: sigmoid((Vn+20)/3) = t/(1+t) = eA*rr */                         \
    float sg = eA * rr;                                                       \
    if (s3) *outp = sg;                                                       \
    outp += L_;                                                               \
  }

__global__ __launch_bounds__(64) void hh_kernel(const float* __restrict__ z,
                                                float* __restrict__ out) {
    const int t   = blockIdx.x * 64 + threadIdx.x;    // 0 .. 65535
    const int sub = t & 3;                             // quad role
    const int ch  = t >> 2;                            // chain 0..16383
    const int b   = ch >> 10;
    const int l   = ch & 1023;
    const int base = b * (N_ * L_) + l;

    const bool isM = (sub == 0);
    const bool isN = (sub == 1);
    const bool s3  = (sub == 3);

    const float K9  = 0.16029944898766259f;   // log2(e)/9
    const float K12 = 0.12022458674074695f;   // log2(e)/12
    const float K3  = 0.48089834696298783f;   // log2(e)/3

    // per-lane steering constants (set once; straight-line steps after)
    float sA1, cA1, sB1, cB1, cD, cu, kA, k2, zm, ks1, ks0, kse, cS, zm01;
    float cg, cgad, ce, cead, cc, pA, pS;
    if (sub == 0) {        // m-gate
        sA1 = K9;   cA1 = 35.0f * K9;   sB1 = 0.0f; cB1 = 0.0f;
        cD  = -1.0f; cu = 35.0f;  kA = 0.182f; k2 = 0.0f; zm = 0.0f;
        ks1 = 0.00306f; ks0 = 0.00182f; kse = 0.0f; cS = 0.0f; zm01 = 0.0f;
        cg = 0.40f; cgad = 0.0f;    ce = 2200.0f;  cead = 0.0f;
        cc = -35.0f; pA = 1.638f; pS = 0.02798f;
    } else if (sub == 1) { // n-gate
        sA1 = K9;   cA1 = -25.0f * K9;  sB1 = 0.0f; cB1 = 0.0f;
        cD  = -1.0f; cu = -25.0f; kA = 0.02f;  k2 = 0.0f; zm = 0.0f;
        ks1 = 0.00022f; ks0 = 0.0002f;  kse = 0.0f; cS = 0.0f; zm01 = 0.0f;
        cg = 0.35f; cgad = 0.0f;    ce = -2695.0f; cead = 0.0f;
        cc = 25.0f;  pA = 0.18f;  pS = 0.0026f;
    } else if (sub == 2) { // h-gate: aH = .25*eA, bH = .25*eB
        sA1 = -K12; cA1 = -90.0f * K12; sB1 = K12;  cB1 = 34.0f * K12;
        cD  = 1.0f;  cu = 0.0f;   kA = 0.0f;   k2 = 0.25f; zm = 0.0f;
        ks1 = 0.0f; ks0 = 0.0f;  kse = 0.0025f; cS = 0.0f; zm01 = 0.0f;
        cg = 0.0f;  cgad = 0.003f;  ce = 0.0f;     cead = -19.5f;
        cc = 1e30f;  pA = 0.0f;   pS = 0.0f;
    } else {               // y-gate + sigmoid/store: eA = exp((Vn+20)/3)
        sA1 = K3;   cA1 = 20.0f * K3;   sB1 = 0.0f; cB1 = 0.0f;
        cD  = 1.0f;  cu = 0.0f;   kA = 0.0f;   k2 = 0.0f;  zm = 1.0f;
        ks1 = 0.0f; ks0 = 0.0f;  kse = 0.0f;    cS = 0.001f; zm01 = 0.01f;
        cg = 0.01f; cgad = 0.0f;    ce = 0.0f;     cead = 0.0f;
        cc = 1e30f;  pA = 0.0f;   pS = 0.0f;
    }

    float V  = -70.0f;
    float st = (sub == 2) ? 1.0f : 0.0f;   // m,n,y = 0; h = 1

    float zb[8];
    const float* zp0 = z + base;
#pragma unroll
    for (int i = 0; i < 8; ++i) zb[i] = zp0[i * L_];
    const float* zpre = z + base + 8 * L_;
    float* outp = out + base + L_;

    if (s3) out[base] = 5.777750e-8f;      // row 0: sigmoid((-70+20)/3)

    for (int g = 0; g < 249; ++g) {        // steps 1 .. 1992
#pragma unroll
        for (int j = 0; j < 8; ++j) STEP1(j, true)
    }
#pragma unroll
    for (int j = 0; j < 7; ++j) STEP1(j, false)   // steps 1993 .. 1999
}

extern "C" void kernel_launch(void* const* d_in, const int* in_sizes, int n_in,
                              void* d_out, int out_size, void* d_ws, size_t ws_size,
                              hipStream_t stream) {
    const float* z = (const float*)d_in[0];
    float* out = (float*)d_out;
    // 16384 chains x 4 lanes = 65536 threads = 1024 waves (1 per SIMD, all SIMDs)
    hh_kernel<<<1024, 64, 0, stream>>>(z, out);
}